// Round 2
// baseline (716.773 us; speedup 1.0000x reference)
//
#include <hip/hip_runtime.h>
#include <stdint.h>

#define TT 512
#define BB 32
#define EE 512
#define HH 2048

typedef __attribute__((ext_vector_type(8))) short short8;   // 8 x bf16 (4 VGPRs)
typedef __attribute__((ext_vector_type(4))) float f32x4;    // MFMA accumulator

// LDS geometry (in shorts)
#define XROW 528            // 512 data + 16 pad: measured 0 bank conflicts (R1/R3/R6);
                            // 520 gave 8.4M conflicts (R4). Row stride 1056 B = 16*66.
#define XBUF (16 * XROW)    // one 16-t chunk buffer = 8448 shorts (16.5 KB)

static __device__ __forceinline__ unsigned short f2bf(float f) {
    union { float f; unsigned u; } v; v.f = f;
    unsigned u = v.u;
    unsigned r = u + 0x7FFFu + ((u >> 16) & 1u);   // round-to-nearest-even
    return (unsigned short)(r >> 16);
}

static __device__ __forceinline__ float fast_exp(float x) {
    return __builtin_amdgcn_exp2f(x * 1.44269504f);
}
static __device__ __forceinline__ float fast_rcp(float x) {
    return __builtin_amdgcn_rcpf(x);
}

// Async global->LDS DMA, 16 B/lane (wave-uniform LDS base + lane*16).
// Verified correct in R4 (passed, absmax 0.0039).
static __device__ __forceinline__ void load_lds16(const unsigned short* g, unsigned short* l) {
    __builtin_amdgcn_global_load_lds(
        (const __attribute__((address_space(1))) unsigned int*)(uintptr_t)g,
        (__attribute__((address_space(3))) unsigned int*)(uintptr_t)l,
        16, 0, 0);
}

// ---------------------------------------------------------------------------
// Pre-kernel: convert sent (T,B,E) fp32 and W (3H,E) fp32 to bf16 in ws.
// ---------------------------------------------------------------------------
__global__ void convert_inputs(const float* __restrict__ X,
                               const float* __restrict__ W,
                               unsigned short* __restrict__ Xb,
                               unsigned short* __restrict__ Wb) {
    const int nX = TT * BB * EE;              // 8,388,608 (divisible by 8)
    int i = (blockIdx.x * blockDim.x + threadIdx.x) * 8;
    const float* src;
    unsigned short* dst;
    int j;
    if (i < nX) { src = X; dst = Xb; j = i; }
    else        { src = W; dst = Wb; j = i - nX; }
    float4 v0 = *(const float4*)(src + j);
    float4 v1 = *(const float4*)(src + j + 4);
    union { short8 s; unsigned short u[8]; } o;
    o.u[0] = f2bf(v0.x); o.u[1] = f2bf(v0.y); o.u[2] = f2bf(v0.z); o.u[3] = f2bf(v0.w);
    o.u[4] = f2bf(v1.x); o.u[5] = f2bf(v1.y); o.u[6] = f2bf(v1.z); o.u[7] = f2bf(v1.w);
    *(short8*)(dst + j) = o.s;
}

// ---------------------------------------------------------------------------
// Fused QRNN kernel — R6 restructure: 512-thread / 64-h blocks.
//
// R5 counters showed occupancy 20% with 46 KB LDS (<=3 blocks/CU) and 2048
// blocks = 8 blocks/CU run in 3-4 sequential ROUNDS; total = rounds x
// block_life (round-quantized). The X LDS buffer depends only on b, so two
// 32-h blocks merged into one 512-thread block SHARE it: LDS goes
// 46,080 -> 58,368 B (exch doubles, X unchanged) -> still 2 blocks/CU
// = 16 waves/CU, grid 1024 -> 4 blocks/CU -> 2 rounds. Per-wave work,
// W AGPR pinning, DMA staging, rotation pipeline, hazard set: unchanged
// from the verified R5 structure.
//
// 8 waves = 4 h-tiles (hi = wv>>1) x 2 k-halves (s = wv&1).
// - Region ch issues MFMA(ch) but runs tail(ch-1) on `prev` accumulators
//   (matrix-pipe / VALU overlap, m114).
// - exch read for tail(ch-1) issued EARLY (before MFMA burst); slot safety:
//   read slot (ch-1)&1 vs publish slot ch&1 differ; overwrite of (ch-1)&1
//   is publish(ch+1), on the far side of barrier(ch).
// - XCD swizzle: 4 b's per XCD (1024 = 8 xcd x 4 b x 32 hgrp); the 32
//   blocks of one b share the 512 KB X b-slice in that XCD's L2.
// - ONE __syncthreads per chunk. Hazards: (1) publish vs tail-read:
//   barrier(ch). (2) tail-read(ch) vs re-publish(ch+2): barrier(ch+1).
//   (3) X buf reread/rewrite: lgkm drained at barrier. (4) stage(ch+1) DMA
//   vs consume in ch+1: vmcnt drained at barrier(ch).
// ---------------------------------------------------------------------------
__launch_bounds__(512, 4)
__global__ void qrnn_fused(const unsigned short* __restrict__ Xb, // bf16 (T,B,E)
                           const unsigned short* __restrict__ Wb, // bf16 (3H,E)
                           const float* __restrict__ bias,        // (3H)
                           float* __restrict__ out)               // (B,H) fp32
{
    __shared__ unsigned short xlds[2 * XBUF];      // 33,792 B
    __shared__ float exch[2][4][64][12];           // 24,576 B  (total 58,368 B)

    const int tid  = threadIdx.x;
    const int wv   = tid >> 6;         // wave 0..7
    const int lane = tid & 63;
    const int q    = lane >> 4;        // quad 0..3
    const int c    = lane & 15;        // column within 16x16 tile
    const int hi   = wv >> 1;          // h-tile 0..3
    const int s    = wv & 1;           // k-half 0..1

    // XCD-aware swizzle: 1024 blocks = 8 XCDs x 4 batches x 32 h-groups.
    const int id   = blockIdx.x;       // 0..1023
    const int xcd  = id & 7;
    const int slot = id >> 3;          // 0..127 within this XCD
    const int b    = xcd * 4 + (slot >> 5);   // 4 batches per XCD
    const int hgrp = slot & 31;               // 32 h-groups (64 h each) per batch
    const int h    = hgrp * 64 + hi * 16 + c;

    // ---- preload W fragments (this wave's K half); pin into AGPRs ----
    // B-frag layout for 16x16x32: lane holds n = lane&15 (= h), k = q*8 + j.
    short8 wz[8], wf[8], wo[8];
    {
        const unsigned short* wzr = Wb + (size_t)h * EE            + s * 256;
        const unsigned short* wfr = Wb + (size_t)(HH + h) * EE     + s * 256;
        const unsigned short* wor = Wb + (size_t)(2 * HH + h) * EE + s * 256;
#pragma unroll
        for (int k = 0; k < 8; ++k) {
            int e0 = k * 32 + q * 8;
            wz[k] = *(const short8*)(wzr + e0);
            wf[k] = *(const short8*)(wfr + e0);
            wo[k] = *(const short8*)(wor + e0);
        }
    }
    // Liveness pin in AGPR class: loads happen once, stay resident (R3/R4
    // verified: no refetch, no spill).
#pragma unroll
    for (int k = 0; k < 8; ++k) {
        asm volatile("" : "+a"(wz[k]), "+a"(wf[k]), "+a"(wo[k]));
    }

    const float b0 = (s == 0) ? bias[h]          : 0.0f;
    const float b1 = (s == 0) ? bias[HH + h]     : 0.0f;
    const float b2 = (s == 0) ? bias[2 * HH + h] : 0.0f;

    float carry = 0.0f;
    float vmax  = -1e30f;

    // ---- staging: wave wv owns rows wv*2, wv*2+1 of each 16-t chunk ----
    const unsigned short* g0 = Xb + ((size_t)(wv * 2) * BB + b) * EE + lane * 8;
    unsigned short* l0 = &xlds[(wv * 2) * XROW];

    auto stage = [&](int n, int slt) {
        const unsigned short* g = g0 + (size_t)n * (16 * BB * EE);
        unsigned short* l = l0 + slt * XBUF;
#pragma unroll
        for (int i = 0; i < 2; ++i)
            load_lds16(g + (size_t)i * (BB * EE), l + i * XROW);
    };

    // tail for one chunk's fully-summed accumulators (s==0 waves only):
    // activations, 16-step affine scan (4 in-lane + cross-quad), carry, max.
    auto do_tail = [&](f32x4 az, f32x4 af, f32x4 ao) {
        float aa[4], mm[4], oo[4];
#pragma unroll
        for (int r = 0; r < 4; ++r) {
            float e2 = fast_exp(2.0f * az[r]);
            float z  = 1.0f - 2.0f * fast_rcp(e2 + 1.0f);  // tanh
            float f  = fast_rcp(1.0f + fast_exp(-af[r]));  // sigmoid
            float o  = fast_rcp(1.0f + fast_exp(-ao[r]));  // sigmoid
            aa[r] = f * z;
            mm[r] = 1.0f - f;
            oo[r] = o;
        }

        // affine scan: compose 4 steps, scan across quads
        float A = aa[0], M = mm[0];
#pragma unroll
        for (int r = 1; r < 4; ++r) { A = aa[r] + mm[r] * A; M = mm[r] * M; }

        float Ap = __shfl_up(A, 16, 64), Mp = __shfl_up(M, 16, 64);
        if (q >= 1) { A = A + M * Ap; M = M * Mp; }
        Ap = __shfl_up(A, 32, 64); Mp = __shfl_up(M, 32, 64);
        if (q >= 2) { A = A + M * Ap; M = M * Mp; }
        float Ae = __shfl_up(A, 16, 64), Me = __shfl_up(M, 16, 64);
        if (q == 0) { Ae = 0.0f; Me = 1.0f; }
        float cc = Ae + Me * carry;

#pragma unroll
        for (int r = 0; r < 4; ++r) {
            cc = aa[r] + mm[r] * cc;
            vmax = fmaxf(vmax, oo[r] * cc);
        }

        float cend = A + M * carry;
        carry = __shfl(cend, 48 + c, 64);
    };

    stage(0, 0);
    __syncthreads();

    f32x4 prevz, prevf, prevo;   // MFMA results of chunk ch-1 (rotation state)

    for (int ch = 0; ch < 32; ++ch) {
        const int buf = ch & 1;
        if (ch < 31) stage(ch + 1, buf ^ 1);

        // ---- prefetch ALL A-frags for this chunk (8 back-to-back b128) ----
        // lane holds m = lane&15 (= t within chunk), k = q*8 + j
        const unsigned short* Abase = &xlds[buf * XBUF + c * XROW + s * 256 + q * 8];
        short8 a[8];
#pragma unroll
        for (int k = 0; k < 8; ++k)
            a[k] = *(const short8*)(Abase + k * 32);

        // ---- early exchange read for tail(ch-1): LDS latency hides under
        //      the MFMA burst below. Slot (ch-1)&1 is stable in this region.
        f32x4 pz, pf, po;
        if (s == 0 && ch > 0) {
            const float* e = &exch[(ch - 1) & 1][hi][lane][0];
            pz = *(const f32x4*)(e);
            pf = *(const f32x4*)(e + 4);
            po = *(const f32x4*)(e + 8);
        }

        // ---- MFMA burst: 24 MFMAs, 3 independent accumulator chains ----
        f32x4 az = {b0, b0, b0, b0};
        f32x4 af = {b1, b1, b1, b1};
        f32x4 ao = {b2, b2, b2, b2};
#pragma unroll
        for (int k = 0; k < 8; ++k) {
            az = __builtin_amdgcn_mfma_f32_16x16x32_bf16(a[k], wz[k], az, 0, 0, 0);
            af = __builtin_amdgcn_mfma_f32_16x16x32_bf16(a[k], wf[k], af, 0, 0, 0);
            ao = __builtin_amdgcn_mfma_f32_16x16x32_bf16(a[k], wo[k], ao, 0, 0, 0);
        }

        // ---- s=1 publishes THIS chunk's partials into its ping-pong slot ----
        if (s == 1) {
            float* e = &exch[ch & 1][hi][lane][0];
            *(f32x4*)(e)     = az;
            *(f32x4*)(e + 4) = af;
            *(f32x4*)(e + 8) = ao;
        }

        // ---- tail(ch-1): pure VALU on prev* + p*; no dependency on the
        //      MFMAs just issued -> overlaps the matrix pipe.
        if (s == 0 && ch > 0) {
            do_tail(prevz + pz, prevf + pf, prevo + po);
        }

        prevz = az; prevf = af; prevo = ao;

        __syncthreads();   // the ONE barrier per chunk: orders publish(ch) vs
                           // read(ch) next region, drains stage(ch+1) DMA,
                           // and fences buf reuse (lgkm+vmcnt drained).
    }

    // ---- epilogue: tail(31) (its exch slot was published in region 31) ----
    if (s == 0) {
        const float* e = &exch[31 & 1][hi][lane][0];
        f32x4 pz = *(const f32x4*)(e);
        f32x4 pf = *(const f32x4*)(e + 4);
        f32x4 po = *(const f32x4*)(e + 8);
        do_tail(prevz + pz, prevf + pf, prevo + po);

        vmax = fmaxf(vmax, __shfl_xor(vmax, 16, 64));
        vmax = fmaxf(vmax, __shfl_xor(vmax, 32, 64));
        if (q == 0) out[(size_t)b * HH + h] = vmax;
    }
}

// ---------------------------------------------------------------------------
extern "C" void kernel_launch(void* const* d_in, const int* in_sizes, int n_in,
                              void* d_out, int out_size, void* d_ws, size_t ws_size,
                              hipStream_t stream) {
    const float* sent = (const float*)d_in[0];
    // d_in[1] = lengths (unused by the math)
    const float* W    = (const float*)d_in[2];
    const float* bias = (const float*)d_in[3];
    float* out        = (float*)d_out;

    const int nX = TT * BB * EE;        // 8,388,608
    const int nW = 3 * HH * EE;         // 3,145,728
    unsigned short* Xb = (unsigned short*)d_ws;
    unsigned short* Wb = Xb + nX;       // 16 MiB offset, 16B-aligned

    int totalVec = (nX + nW) / 8;       // 1,441,792 threads, exact cover
    convert_inputs<<<totalVec / 256, 256, 0, stream>>>(sent, W, Xb, Wb);

    dim3 grid(1024);                    // 1-D: swizzled to (xcd, b, hgrp) in-kernel
    qrnn_fused<<<grid, 512, 0, stream>>>(Xb, Wb, bias, out);
}

// Round 3
// 244.666 us; speedup vs baseline: 2.9296x; 2.9296x over previous
//
#include <hip/hip_runtime.h>
#include <stdint.h>

#define TT 512
#define BB 32
#define EE 512
#define HH 2048

typedef __attribute__((ext_vector_type(8))) short short8;   // 8 x bf16 (4 VGPRs)
typedef __attribute__((ext_vector_type(4))) float f32x4;    // MFMA accumulator

// LDS geometry (in shorts)
#define XROW 528            // 512 data + 16 pad: measured 0 bank conflicts (R1/R3/R6);
                            // 520 gave 8.4M conflicts (R4). Row stride 1056 B = 16*66.
#define XBUF (16 * XROW)    // one 16-t chunk buffer = 8448 shorts (16.5 KB)

// Counted-vmcnt barriers (T3/T4). Each wave issues exactly 4 global_load_lds
// per stage; vmcnt(4) retires the OLDEST 4 (stage ch+1) while leaving the 4
// just-issued (stage ch+2) in flight across the barrier. lgkmcnt(0) orders
// all DS ops (a-frag reads, exch publish) before the barrier. "memory"
// clobber = compiler memory fence for the C++ LDS ops on both sides.
#define BAR_VM4() asm volatile("s_waitcnt vmcnt(4) lgkmcnt(0)\n\ts_barrier" ::: "memory")
#define BAR_VM0() asm volatile("s_waitcnt vmcnt(0) lgkmcnt(0)\n\ts_barrier" ::: "memory")

static __device__ __forceinline__ unsigned short f2bf(float f) {
    union { float f; unsigned u; } v; v.f = f;
    unsigned u = v.u;
    unsigned r = u + 0x7FFFu + ((u >> 16) & 1u);   // round-to-nearest-even
    return (unsigned short)(r >> 16);
}

static __device__ __forceinline__ float fast_exp(float x) {
    return __builtin_amdgcn_exp2f(x * 1.44269504f);
}
static __device__ __forceinline__ float fast_rcp(float x) {
    return __builtin_amdgcn_rcpf(x);
}

// Async global->LDS DMA, 16 B/lane (wave-uniform LDS base + lane*16).
// Verified correct in R4 (passed, absmax 0.0039).
static __device__ __forceinline__ void load_lds16(const unsigned short* g, unsigned short* l) {
    __builtin_amdgcn_global_load_lds(
        (const __attribute__((address_space(1))) unsigned int*)(uintptr_t)g,
        (__attribute__((address_space(3))) unsigned int*)(uintptr_t)l,
        16, 0, 0);
}

// ---------------------------------------------------------------------------
// Pre-kernel: convert sent (T,B,E) fp32 and W (3H,E) fp32 to bf16 in ws.
// ---------------------------------------------------------------------------
__global__ void convert_inputs(const float* __restrict__ X,
                               const float* __restrict__ W,
                               unsigned short* __restrict__ Xb,
                               unsigned short* __restrict__ Wb) {
    const int nX = TT * BB * EE;              // 8,388,608 (divisible by 8)
    int i = (blockIdx.x * blockDim.x + threadIdx.x) * 8;
    const float* src;
    unsigned short* dst;
    int j;
    if (i < nX) { src = X; dst = Xb; j = i; }
    else        { src = W; dst = Wb; j = i - nX; }
    float4 v0 = *(const float4*)(src + j);
    float4 v1 = *(const float4*)(src + j + 4);
    union { short8 s; unsigned short u[8]; } o;
    o.u[0] = f2bf(v0.x); o.u[1] = f2bf(v0.y); o.u[2] = f2bf(v0.z); o.u[3] = f2bf(v0.w);
    o.u[4] = f2bf(v1.x); o.u[5] = f2bf(v1.y); o.u[6] = f2bf(v1.z); o.u[7] = f2bf(v1.w);
    *(short8*)(dst + j) = o.s;
}

// ---------------------------------------------------------------------------
// Fused QRNN kernel — R7: R1-verified 256-thread structure + depth-2 DMA
// pipeline with counted vmcnt (T3/T4).
//
// R2 post-mortem: __launch_bounds__(512,4) forced <=128 regs/wave vs the ~196
// needed (100 VGPR + 96 AGPR W-pin) -> spill to scratch (WRITE_SIZE 256KB ->
// 145MB, FETCH 105MB -> 2.26GB). REVERTED. Registers (2 waves/SIMD) are the
// residency limiter, not LDS.
//
// This round's single change: 3 X buffers, stage(ch+2) issued in region ch,
// and the per-chunk __syncthreads (which drains vmcnt(0), exposing the full
// DMA latency every chunk) replaced by `s_waitcnt vmcnt(4) lgkmcnt(0);
// s_barrier`. The DMA for buf(ch+1) now has ~2 full regions to land.
//
// Hazard set (re-derived for depth-2):
//  (1) publish(ch) vs tail-read(ch) in region ch+1: lgkmcnt(0)+barrier(ch).
//  (2) tail-read(ch) vs re-publish(ch+2): barrier(ch+1).
//  (3) X buf WAR: stage(ch+2) writes buf (ch+2)%3, whose last readers ran in
//      region ch-1 and retired at barrier(ch-1) (lgkmcnt(0)) before ANY wave
//      issues its region-ch stage (barrier orders the block).
//  (4) X buf RAW: region ch+1 reads buf (ch+1)%3; its 4 DMA loads are the
//      oldest outstanding at barrier(ch) -> vmcnt(4) retires them.
//  (5) Barriers wave-uniform: ch is uniform; all 256 threads hit every
//      barrier exactly once per region.
// ---------------------------------------------------------------------------
__launch_bounds__(256, 2)
__global__ void qrnn_fused(const unsigned short* __restrict__ Xb, // bf16 (T,B,E)
                           const unsigned short* __restrict__ Wb, // bf16 (3H,E)
                           const float* __restrict__ bias,        // (3H)
                           float* __restrict__ out)               // (B,H) fp32
{
    __shared__ unsigned short xlds[3 * XBUF];      // 50,688 B
    __shared__ float exch[2][2][64][12];           // 12,288 B  (total 62,976 B)

    const int tid  = threadIdx.x;
    const int wv   = tid >> 6;         // wave 0..3
    const int lane = tid & 63;
    const int q    = lane >> 4;        // quad 0..3
    const int c    = lane & 15;        // column within 16x16 tile
    const int hi   = wv >> 1;          // h-tile 0..1
    const int s    = wv & 1;           // k-half 0..1

    // XCD-aware swizzle: 2048 blocks = 8 XCDs x 4 batches x 64 h-groups.
    const int id   = blockIdx.x;       // 0..2047
    const int xcd  = id & 7;
    const int slot = id >> 3;          // 0..255 within this XCD
    const int b    = xcd * 4 + (slot >> 6);   // 4 batches per XCD
    const int hgrp = slot & 63;               // 64 h-groups per batch
    const int h    = hgrp * 32 + hi * 16 + c;

    // ---- preload W fragments (this wave's K half); pin into AGPRs ----
    // B-frag layout for 16x16x32: lane holds n = lane&15 (= h), k = q*8 + j.
    short8 wz[8], wf[8], wo[8];
    {
        const unsigned short* wzr = Wb + (size_t)h * EE            + s * 256;
        const unsigned short* wfr = Wb + (size_t)(HH + h) * EE     + s * 256;
        const unsigned short* wor = Wb + (size_t)(2 * HH + h) * EE + s * 256;
#pragma unroll
        for (int k = 0; k < 8; ++k) {
            int e0 = k * 32 + q * 8;
            wz[k] = *(const short8*)(wzr + e0);
            wf[k] = *(const short8*)(wfr + e0);
            wo[k] = *(const short8*)(wor + e0);
        }
    }
    // Liveness pin in AGPR class: loads happen once, stay resident (R3/R4
    // verified: no refetch, no spill).
#pragma unroll
    for (int k = 0; k < 8; ++k) {
        asm volatile("" : "+a"(wz[k]), "+a"(wf[k]), "+a"(wo[k]));
    }

    const float b0 = (s == 0) ? bias[h]          : 0.0f;
    const float b1 = (s == 0) ? bias[HH + h]     : 0.0f;
    const float b2 = (s == 0) ? bias[2 * HH + h] : 0.0f;

    float carry = 0.0f;
    float vmax  = -1e30f;

    // ---- staging: wave wv owns rows wv*4 .. wv*4+3 of each 16-t chunk ----
    const unsigned short* g0 = Xb + ((size_t)(wv * 4) * BB + b) * EE + lane * 8;
    unsigned short* l0 = &xlds[(wv * 4) * XROW];

    auto stage = [&](int n, int slt) {
        const unsigned short* g = g0 + (size_t)n * (16 * BB * EE);
        unsigned short* l = l0 + slt * XBUF;
#pragma unroll
        for (int i = 0; i < 4; ++i)
            load_lds16(g + (size_t)i * (BB * EE), l + i * XROW);
    };

    // tail for one chunk's fully-summed accumulators (s==0 waves only):
    // activations, 16-step affine scan (4 in-lane + cross-quad), carry, max.
    auto do_tail = [&](f32x4 az, f32x4 af, f32x4 ao) {
        float aa[4], mm[4], oo[4];
#pragma unroll
        for (int r = 0; r < 4; ++r) {
            float e2 = fast_exp(2.0f * az[r]);
            float z  = 1.0f - 2.0f * fast_rcp(e2 + 1.0f);  // tanh
            float f  = fast_rcp(1.0f + fast_exp(-af[r]));  // sigmoid
            float o  = fast_rcp(1.0f + fast_exp(-ao[r]));  // sigmoid
            aa[r] = f * z;
            mm[r] = 1.0f - f;
            oo[r] = o;
        }

        // affine scan: compose 4 steps, scan across quads
        float A = aa[0], M = mm[0];
#pragma unroll
        for (int r = 1; r < 4; ++r) { A = aa[r] + mm[r] * A; M = mm[r] * M; }

        float Ap = __shfl_up(A, 16, 64), Mp = __shfl_up(M, 16, 64);
        if (q >= 1) { A = A + M * Ap; M = M * Mp; }
        Ap = __shfl_up(A, 32, 64); Mp = __shfl_up(M, 32, 64);
        if (q >= 2) { A = A + M * Ap; M = M * Mp; }
        float Ae = __shfl_up(A, 16, 64), Me = __shfl_up(M, 16, 64);
        if (q == 0) { Ae = 0.0f; Me = 1.0f; }
        float cc = Ae + Me * carry;

#pragma unroll
        for (int r = 0; r < 4; ++r) {
            cc = aa[r] + mm[r] * cc;
            vmax = fmaxf(vmax, oo[r] * cc);
        }

        float cend = A + M * carry;
        carry = __shfl(cend, 48 + c, 64);
    };

    // ---- prologue: fill the depth-2 pipeline ----
    stage(0, 0);
    stage(1, 1);
    BAR_VM4();   // retire stage(0) (oldest 4); stage(1) stays in flight

    f32x4 prevz, prevf, prevo;   // MFMA results of chunk ch-1 (rotation state)

    for (int ch = 0; ch < 32; ++ch) {
        const int buf = ch % 3;
        if (ch < 30) stage(ch + 2, (ch + 2) % 3);

        // ---- prefetch ALL A-frags for this chunk (8 back-to-back b128) ----
        // lane holds m = lane&15 (= t within chunk), k = q*8 + j
        const unsigned short* Abase = &xlds[buf * XBUF + c * XROW + s * 256 + q * 8];
        short8 a[8];
#pragma unroll
        for (int k = 0; k < 8; ++k)
            a[k] = *(const short8*)(Abase + k * 32);

        // ---- early exchange read for tail(ch-1): LDS latency hides under
        //      the MFMA burst below. Slot (ch-1)&1 is stable in this region.
        f32x4 pz, pf, po;
        if (s == 0 && ch > 0) {
            const float* e = &exch[(ch - 1) & 1][hi][lane][0];
            pz = *(const f32x4*)(e);
            pf = *(const f32x4*)(e + 4);
            po = *(const f32x4*)(e + 8);
        }

        // ---- MFMA burst: 24 MFMAs, 3 independent accumulator chains ----
        f32x4 az = {b0, b0, b0, b0};
        f32x4 af = {b1, b1, b1, b1};
        f32x4 ao = {b2, b2, b2, b2};
#pragma unroll
        for (int k = 0; k < 8; ++k) {
            az = __builtin_amdgcn_mfma_f32_16x16x32_bf16(a[k], wz[k], az, 0, 0, 0);
            af = __builtin_amdgcn_mfma_f32_16x16x32_bf16(a[k], wf[k], af, 0, 0, 0);
            ao = __builtin_amdgcn_mfma_f32_16x16x32_bf16(a[k], wo[k], ao, 0, 0, 0);
        }

        // ---- s=1 publishes THIS chunk's partials into its ping-pong slot ----
        if (s == 1) {
            float* e = &exch[ch & 1][hi][lane][0];
            *(f32x4*)(e)     = az;
            *(f32x4*)(e + 4) = af;
            *(f32x4*)(e + 8) = ao;
        }

        // ---- tail(ch-1): pure VALU on prev* + p*; no dependency on the
        //      MFMAs just issued -> overlaps the matrix pipe.
        if (s == 0 && ch > 0) {
            do_tail(prevz + pz, prevf + pf, prevo + po);
        }

        prevz = az; prevf = af; prevo = ao;

        // ---- counted-vmcnt barrier: retire stage(ch+1), keep stage(ch+2)
        //      in flight. Tail of the pipeline drains fully.
        if (ch < 30) BAR_VM4(); else BAR_VM0();
    }

    // ---- epilogue: tail(31) (its exch slot was published in region 31) ----
    if (s == 0) {
        const float* e = &exch[31 & 1][hi][lane][0];
        f32x4 pz = *(const f32x4*)(e);
        f32x4 pf = *(const f32x4*)(e + 4);
        f32x4 po = *(const f32x4*)(e + 8);
        do_tail(prevz + pz, prevf + pf, prevo + po);

        vmax = fmaxf(vmax, __shfl_xor(vmax, 16, 64));
        vmax = fmaxf(vmax, __shfl_xor(vmax, 32, 64));
        if (q == 0) out[(size_t)b * HH + h] = vmax;
    }
}

// ---------------------------------------------------------------------------
extern "C" void kernel_launch(void* const* d_in, const int* in_sizes, int n_in,
                              void* d_out, int out_size, void* d_ws, size_t ws_size,
                              hipStream_t stream) {
    const float* sent = (const float*)d_in[0];
    // d_in[1] = lengths (unused by the math)
    const float* W    = (const float*)d_in[2];
    const float* bias = (const float*)d_in[3];
    float* out        = (float*)d_out;

    const int nX = TT * BB * EE;        // 8,388,608
    const int nW = 3 * HH * EE;         // 3,145,728
    unsigned short* Xb = (unsigned short*)d_ws;
    unsigned short* Wb = Xb + nX;       // 16 MiB offset, 16B-aligned

    int totalVec = (nX + nW) / 8;       // 1,441,792 threads, exact cover
    convert_inputs<<<totalVec / 256, 256, 0, stream>>>(sent, W, Xb, Wb);

    dim3 grid(2048);                    // 1-D: swizzled to (xcd, b, hgrp) in-kernel
    qrnn_fused<<<grid, 256, 0, stream>>>(Xb, Wb, bias, out);
}